// Round 4
// baseline (1116.175 us; speedup 1.0000x reference)
//
#include <hip/hip_runtime.h>
#include <hip/hip_bf16.h>
#include <stdint.h>

// Problem constants
#define B_ROWS 32768
#define KTOT   3584   // 1024 + 512 + 2048 (concat of stream features)
#define NC     6144   // C panels: out_a|out_b|out_c|gate(3072)
#define OUT_N  1024

typedef unsigned short ushort_t;
typedef __attribute__((ext_vector_type(8))) short bf16x8;
typedef __attribute__((ext_vector_type(4))) float f32x4;

__device__ __forceinline__ float b2f(unsigned short u) {
    union { unsigned int i; float f; } x; x.i = ((unsigned int)u) << 16; return x.f;
}
__device__ __forceinline__ unsigned short f2b(float f) {
    union { float f; unsigned int i; } x; x.f = f;
    unsigned int r = x.i + 0x7fffu + ((x.i >> 16) & 1u);
    return (unsigned short)(r >> 16);
}

// async global->LDS, 16B per lane
__device__ __forceinline__ void gload_lds16(const void* g, void* l) {
    auto g1 = reinterpret_cast<const __attribute__((address_space(1))) char*>(
        reinterpret_cast<uintptr_t>(g));
    auto l3 = reinterpret_cast<__attribute__((address_space(3))) char*>(
        (uint32_t)reinterpret_cast<uintptr_t>(l));
    __builtin_amdgcn_global_load_lds(g1, l3, 16, 0, 0);
}

// ds_read_b128 with compile-time offset
template<int OFF>
__device__ __forceinline__ bf16x8 dsr(uint32_t addr) {
    bf16x8 d;
    asm volatile("ds_read_b128 %0, %1 offset:%2" : "=v"(d) : "v"(addr), "i"(OFF));
    return d;
}

// ---------------------------------------------------------------------------
// Kernel 1: weight pack. WT[n][k] (bf16, 4096 x 3584).
// ---------------------------------------------------------------------------
__global__ __launch_bounds__(256) void pack_wt_kernel(
    const float* __restrict__ Wa, const float* __restrict__ Wga,
    const float* __restrict__ Wb, const float* __restrict__ Wgb,
    const float* __restrict__ Wc, const float* __restrict__ Wgc,
    ushort_t* __restrict__ WT)
{
    int s = blockIdx.y;
    const float *Ws, *Wgs; int d, koff;
    if (s == 0)      { Ws = Wa; Wgs = Wga; d = 1024; koff = 0;    }
    else if (s == 1) { Ws = Wb; Wgs = Wgb; d = 512;  koff = 1024; }
    else             { Ws = Wc; Wgs = Wgc; d = 2048; koff = 1536; }
    int kt = blockIdx.x >> 6;
    int ntile = blockIdx.x & 63;
    if (kt >= (d >> 6)) return;
    int k0 = kt * 64, n0 = ntile * 64;
    const float* src; int ld, ncol0;
    if (n0 < 1024) { src = Ws;  ld = 1024; ncol0 = n0; }
    else           { src = Wgs; ld = 3072; ncol0 = n0 - 1024; }

    __shared__ float tile[64][65];
    int tx = threadIdx.x & 63, ty = threadIdx.x >> 6;
    for (int r = ty; r < 64; r += 4)
        tile[r][tx] = src[(size_t)(k0 + r) * ld + ncol0 + tx];
    __syncthreads();
    for (int r = ty; r < 64; r += 4)
        WT[(size_t)(n0 + r) * KTOT + koff + k0 + tx] = f2b(tile[tx][r]);
}

__global__ __launch_bounds__(256) void pack_bias_kernel(
    const float* __restrict__ ba, const float* __restrict__ bb, const float* __restrict__ bc,
    const float* __restrict__ bga, const float* __restrict__ bgb, const float* __restrict__ bgc,
    float* __restrict__ bias)
{
    int i = blockIdx.x * 256 + threadIdx.x;
    if (i >= NC) return;
    float v;
    if (i < 1024)      v = ba[i];
    else if (i < 2048) v = bb[i - 1024];
    else if (i < 3072) v = bc[i - 2048];
    else { int g = i - 3072; v = bga[g] + bgb[g] + bgc[g]; }
    bias[i] = v;
}

// ---------------------------------------------------------------------------
// Kernel 2: LayerNorm + ReLU + cast to bf16, writes F[32768][3584]
// ---------------------------------------------------------------------------
__global__ __launch_bounds__(256) void ln_relu_kernel(
    const float* __restrict__ xa, const float* __restrict__ xb, const float* __restrict__ xc,
    const float* __restrict__ wa, const float* __restrict__ wb, const float* __restrict__ wc,
    const float* __restrict__ ba, const float* __restrict__ bb, const float* __restrict__ bc,
    ushort_t* __restrict__ F)
{
    int row = blockIdx.x;
    int s = blockIdx.y;
    const float *x, *w, *b; int d, koff;
    if (s == 0)      { x = xa; w = wa; b = ba; d = 1024; koff = 0;    }
    else if (s == 1) { x = xb; w = wb; b = bb; d = 512;  koff = 1024; }
    else             { x = xc; w = wc; b = bc; d = 2048; koff = 1536; }
    const float* xr = x + (size_t)row * d;
    int tid = threadIdx.x;

    float s1 = 0.f, s2 = 0.f;
    for (int i = tid * 4; i < d; i += 1024) {
        float4 v = *(const float4*)(xr + i);
        s1 += v.x + v.y + v.z + v.w;
        s2 += v.x * v.x + v.y * v.y + v.z * v.z + v.w * v.w;
    }
    for (int o = 32; o > 0; o >>= 1) {
        s1 += __shfl_down(s1, o, 64);
        s2 += __shfl_down(s2, o, 64);
    }
    __shared__ float red1[4], red2[4], bcast[2];
    int wv = tid >> 6, ln = tid & 63;
    if (ln == 0) { red1[wv] = s1; red2[wv] = s2; }
    __syncthreads();
    if (tid == 0) {
        float t1 = red1[0] + red1[1] + red1[2] + red1[3];
        float t2 = red2[0] + red2[1] + red2[2] + red2[3];
        float mean = t1 / d;
        float var = t2 / d - mean * mean;
        bcast[0] = mean;
        bcast[1] = rsqrtf(var + 1e-5f);
    }
    __syncthreads();
    float mean = bcast[0], rstd = bcast[1];

    ushort_t* Fr = F + (size_t)row * KTOT + koff;
    for (int i = tid * 4; i < d; i += 1024) {
        float4 v  = *(const float4*)(xr + i);
        float4 wv4 = *(const float4*)(w + i);
        float4 bv4 = *(const float4*)(b + i);
        float o0 = fmaxf(0.f, (v.x - mean) * rstd * wv4.x + bv4.x);
        float o1 = fmaxf(0.f, (v.y - mean) * rstd * wv4.y + bv4.y);
        float o2 = fmaxf(0.f, (v.z - mean) * rstd * wv4.z + bv4.z);
        float o3 = fmaxf(0.f, (v.w - mean) * rstd * wv4.w + bv4.w);
        union { ushort_t u[4]; uint2 v2; } pk;
        pk.u[0] = f2b(o0); pk.u[1] = f2b(o1); pk.u[2] = f2b(o2); pk.u[3] = f2b(o3);
        *(uint2*)(Fr + i) = pk.v2;
    }
}

// ---------------------------------------------------------------------------
// Kernel 3: bf16 GEMM, 256x256 tile, BK=64, 8 waves (2Mx4N), dbuf 128KB LDS.
// Barrier-free intra-tile: ONE s_barrier per K-tile. Stage all of T(t+1) at
// tile start (full-tile flight -> boundary vmcnt(0) non-stalling). ds_reads
// issued 2-3 subphases ahead with FIFO-counted lgkmcnt + sched_barrier(0).
// 8 subphases x 8 MFMA per tile.
//
// Grid: XCD-partitioned by N: xcd = bid&7 owns 3 j-tiles (WT slice <= 3.75MB,
// L2-resident) x all 128 row-panels; F-panels shared cross-XCD via L3.
// ---------------------------------------------------------------------------
__global__ __launch_bounds__(512, 2) void gemm_kernel(
    const ushort_t* __restrict__ F, const ushort_t* __restrict__ WT,
    const float* __restrict__ bias, ushort_t* __restrict__ C)
{
    extern __shared__ ushort_t lds_u16[];   // 131072 bytes
    // byte layout: buf0 A @0 (32KB), buf0 B @32KB, buf1 A @64KB, buf1 B @96KB

    // ---- block decode: xcd owns 3 j's, rp-major inner ----
    int bid = blockIdx.x;
    int xcd = bid & 7;
    int local = bid >> 3;          // 0..383
    int rp = local / 3;            // 0..127
    int jj = local - rp * 3;       // 0..2
    int j;
    if (xcd < 4) j = (jj == 0) ? xcd : (jj == 1) ? 8 + xcd : 12 + xcd;
    else         j = (jj == 0) ? xcd : (jj == 1) ? 12 + xcd : 16 + xcd;

    int row0 = rp * 256;
    int n0, koff, klen, c0;
    if (j < 4)       { n0 = j * 256;            koff = 0;    klen = 1024; c0 = j * 256; }
    else if (j < 8)  { n0 = (j - 4) * 256;      koff = 1024; klen = 512;  c0 = 1024 + (j - 4) * 256; }
    else if (j < 12) { n0 = (j - 8) * 256;      koff = 1536; klen = 2048; c0 = 2048 + (j - 8) * 256; }
    else             { n0 = 1024 + (j - 12) * 256; koff = 0; klen = 3584; c0 = 3072 + (j - 12) * 256; }

    int tid = threadIdx.x, w = tid >> 6, l = tid & 63;
    int wm0 = (w >> 2) * 128;   // wave M origin (2 M-waves)
    int wn0 = (w & 3) * 64;     // wave N origin (4 N-waves)

    // ---- staging source (pre-swizzled so linear LDS dest == swizzled layout)
    int srow = w * 32 + (l >> 3);
    int scol = (((l & 7) ^ (l >> 3)) << 3);
    const ushort_t* Ag = F  + (size_t)(row0 + srow) * KTOT + koff + scol;
    const ushort_t* Bg = WT + (size_t)(n0   + srow) * KTOT + koff + scol;

    uint32_t lds_base = (uint32_t)(uintptr_t)lds_u16;
    uint32_t ldsStA = lds_base + (uint32_t)w * 4096u;

#define STG_A(SELOFF, kt, JJ0) do {                                              \
        gload_lds16(Ag + (size_t)(kt) * 64 + (size_t)(JJ0) * 8 * KTOT,           \
                    (void*)(uintptr_t)(ldsStA + (SELOFF) + (JJ0) * 1024u));      \
        gload_lds16(Ag + (size_t)(kt) * 64 + (size_t)((JJ0) + 1) * 8 * KTOT,     \
                    (void*)(uintptr_t)(ldsStA + (SELOFF) + ((JJ0) + 1) * 1024u)); } while (0)
#define STG_B(SELOFF, kt, JJ0) do {                                              \
        gload_lds16(Bg + (size_t)(kt) * 64 + (size_t)(JJ0) * 8 * KTOT,           \
                    (void*)(uintptr_t)(ldsStA + 32768u + (SELOFF) + (JJ0) * 1024u)); \
        gload_lds16(Bg + (size_t)(kt) * 64 + (size_t)((JJ0) + 1) * 8 * KTOT,     \
                    (void*)(uintptr_t)(ldsStA + 32768u + (SELOFF) + ((JJ0) + 1) * 1024u)); } while (0)

    // ---- ds_read base addrs (swizzled): 16B-col = (ks*4 + (l>>4)) ^ (l&7)
    int rl = l & 15;
    int c16_0 = ((l >> 4)    ) ^ (l & 7);
    int c16_1 = ((l >> 4) + 4) ^ (l & 7);
    uint32_t aA0 = lds_base + (uint32_t)((wm0 + rl) * 128 + c16_0 * 16);
    uint32_t aA1 = lds_base + (uint32_t)((wm0 + rl) * 128 + c16_1 * 16);
    uint32_t aB0 = lds_base + 32768u + (uint32_t)((wn0 + rl) * 128 + c16_0 * 16);
    uint32_t aB1 = lds_base + 32768u + (uint32_t)((wn0 + rl) * 128 + c16_1 * 16);

#define WAITL(N) do { asm volatile("s_waitcnt lgkmcnt(" #N ")" ::: "memory");   \
                      __builtin_amdgcn_sched_barrier(0); } while (0)

#define MFMA8(AV, BV, MI0, NI0) do {                                            \
        __builtin_amdgcn_s_setprio(1);                                          \
        _Pragma("unroll")                                                       \
        for (int mi = 0; mi < 4; ++mi)                                          \
            _Pragma("unroll")                                                   \
            for (int ni = 0; ni < 2; ++ni)                                      \
                acc[(MI0)+mi][(NI0)+ni] = __builtin_amdgcn_mfma_f32_16x16x32_bf16( \
                    AV[mi], BV[ni], acc[(MI0)+mi][(NI0)+ni], 0, 0, 0);          \
        __builtin_amdgcn_s_setprio(0);                                          \
    } while (0)

    f32x4 acc[8][4];
    #pragma unroll
    for (int mi = 0; mi < 8; ++mi)
        #pragma unroll
        for (int ni = 0; ni < 4; ++ni)
            acc[mi][ni] = (f32x4){0.f, 0.f, 0.f, 0.f};

    int nkt = klen >> 6;   // 8..56

    // ---- prologue: stage T0 -> buf0, drain, barrier
    STG_A(0u, 0, 0); STG_A(0u, 0, 2); STG_B(0u, 0, 0); STG_B(0u, 0, 2);
    asm volatile("s_waitcnt vmcnt(0)" ::: "memory");
    __builtin_amdgcn_s_barrier();

    for (int t = 0; t < nkt; ++t) {
        const uint32_t co  = (t & 1) ? 65536u : 0u;
        const uint32_t no_ = co ^ 65536u;
        uint32_t A0 = aA0 + co, A1 = aA1 + co, B0 = aB0 + co, B1 = aB1 + co;

        // stage next tile first (max flight; vmcnt domain only)
        if (t + 1 < nkt) {
            STG_A(no_, t + 1, 0); STG_A(no_, t + 1, 2);
            STG_B(no_, t + 1, 0); STG_B(no_, t + 1, 2);
        }

        bf16x8 alo0[4], alo1[4], ahi0[4], ahi1[4];
        bf16x8 blo0[2], blo1[2], bhi0[2], bhi1[2];

        // G0: alo0(4) + blo0(2)
        alo0[0] = dsr<0>(A0); alo0[1] = dsr<2048>(A0);
        alo0[2] = dsr<4096>(A0); alo0[3] = dsr<6144>(A0);
        blo0[0] = dsr<0>(B0); blo0[1] = dsr<2048>(B0);
        // G1: bhi0(2)
        bhi0[0] = dsr<4096>(B0); bhi0[1] = dsr<6144>(B0);
        // G2: alo1(4) + blo1(2)
        alo1[0] = dsr<0>(A1); alo1[1] = dsr<2048>(A1);
        alo1[2] = dsr<4096>(A1); alo1[3] = dsr<6144>(A1);
        blo1[0] = dsr<0>(B1); blo1[1] = dsr<2048>(B1);

        // S0: (m-lo, n-lo, ks0)   need G0; younger G1+G2 = 8
        WAITL(8);
        MFMA8(alo0, blo0, 0, 0);
        // G3: bhi1(2)
        bhi1[0] = dsr<4096>(B1); bhi1[1] = dsr<6144>(B1);

        // S1: (m-lo, n-hi, ks0)   need G1; younger G2+G3 = 8
        WAITL(8);
        MFMA8(alo0, bhi0, 0, 2);
        // G4: ahi0(4)
        ahi0[0] = dsr<8192>(A0);  ahi0[1] = dsr<10240>(A0);
        ahi0[2] = dsr<12288>(A0); ahi0[3] = dsr<14336>(A0);

        // S2: (m-lo, n-lo, ks1)   need G2; younger G3+G4 = 6
        WAITL(6);
        MFMA8(alo1, blo1, 0, 0);

        // S3: (m-lo, n-hi, ks1)   need G3; younger G4 = 4
        WAITL(4);
        MFMA8(alo1, bhi1, 0, 2);
        // G5: ahi1(4)
        ahi1[0] = dsr<8192>(A1);  ahi1[1] = dsr<10240>(A1);
        ahi1[2] = dsr<12288>(A1); ahi1[3] = dsr<14336>(A1);

        // S4: (m-hi, n-lo, ks0)   need G4; younger G5 = 4
        WAITL(4);
        MFMA8(ahi0, blo0, 4, 0);

        // S5: (m-hi, n-hi, ks0)   operands already resident
        MFMA8(ahi0, bhi0, 4, 2);

        // S6: (m-hi, n-lo, ks1)   need G5
        WAITL(0);
        MFMA8(ahi1, blo1, 4, 0);

        // S7: (m-hi, n-hi, ks1)
        MFMA8(ahi1, bhi1, 4, 2);

        // boundary: T(t+1) landed (full-tile flight), all reads retired
        asm volatile("s_waitcnt vmcnt(0)" ::: "memory");
        __builtin_amdgcn_s_barrier();
    }

#undef STG_A
#undef STG_B
#undef WAITL
#undef MFMA8

    // ---- epilogue: bias + bf16 cast + store
    #pragma unroll
    for (int ni = 0; ni < 4; ++ni) {
        int col = c0 + wn0 + ni * 16 + rl;
        float bv = bias[col];
        #pragma unroll
        for (int mi = 0; mi < 8; ++mi) {
            int rbase = row0 + wm0 + mi * 16 + (l >> 4) * 4;
            #pragma unroll
            for (int r = 0; r < 4; ++r)
                C[(size_t)(rbase + r) * NC + col] = f2b(acc[mi][ni][r] + bv);
        }
    }
}

// ---------------------------------------------------------------------------
// Kernel 4: gate softmax + weighted merge -> d_out (fp32)
// ---------------------------------------------------------------------------
typedef __attribute__((ext_vector_type(8))) unsigned short u16x8;

__global__ __launch_bounds__(256) void fuse_kernel(
    const ushort_t* __restrict__ C, float* __restrict__ out)
{
    int t = blockIdx.x * 256 + threadIdx.x;
    int b  = t >> 7;
    int j0 = (t & 127) << 3;
    const ushort_t* Cr = C + (size_t)b * NC;
    u16x8 oa = *(const u16x8*)(Cr + j0);
    u16x8 ob = *(const u16x8*)(Cr + 1024 + j0);
    u16x8 oc = *(const u16x8*)(Cr + 2048 + j0);
    u16x8 g0 = *(const u16x8*)(Cr + 3072 + j0);
    u16x8 g1 = *(const u16x8*)(Cr + 4096 + j0);
    u16x8 g2 = *(const u16x8*)(Cr + 5120 + j0);
    float res[8];
    #pragma unroll
    for (int k = 0; k < 8; ++k) {
        float a0 = b2f(g0[k]), a1 = b2f(g1[k]), a2 = b2f(g2[k]);
        float m = fmaxf(a0, fmaxf(a1, a2));
        float e0 = __expf(a0 - m), e1 = __expf(a1 - m), e2 = __expf(a2 - m);
        float inv = 1.f / (e0 + e1 + e2);
        res[k] = (e0 * b2f(oa[k]) + e1 * b2f(ob[k]) + e2 * b2f(oc[k])) * inv;
    }
    float* op = out + (size_t)b * 1024 + j0;
    *(float4*)op       = (float4){res[0], res[1], res[2], res[3]};
    *(float4*)(op + 4) = (float4){res[4], res[5], res[6], res[7]};
}

// ---------------------------------------------------------------------------
extern "C" void kernel_launch(void* const* d_in, const int* in_sizes, int n_in,
                              void* d_out, int out_size, void* d_ws, size_t ws_size,
                              hipStream_t stream)
{
    const float* x_a   = (const float*)d_in[0];
    const float* lnw_a = (const float*)d_in[1];
    const float* lnb_a = (const float*)d_in[2];
    const float* W_a   = (const float*)d_in[3];
    const float* b_a   = (const float*)d_in[4];
    const float* Wg_a  = (const float*)d_in[5];
    const float* bg_a  = (const float*)d_in[6];
    const float* x_b   = (const float*)d_in[7];
    const float* lnw_b = (const float*)d_in[8];
    const float* lnb_b = (const float*)d_in[9];
    const float* W_b   = (const float*)d_in[10];
    const float* b_b   = (const float*)d_in[11];
    const float* Wg_b  = (const float*)d_in[12];
    const float* bg_b  = (const float*)d_in[13];
    const float* x_c   = (const float*)d_in[14];
    const float* lnw_c = (const float*)d_in[15];
    const float* lnb_c = (const float*)d_in[16];
    const float* W_c   = (const float*)d_in[17];
    const float* b_c   = (const float*)d_in[18];
    const float* Wg_c  = (const float*)d_in[19];
    const float* bg_c  = (const float*)d_in[20];

    // Workspace layout (total ~667 MB)
    char* ws = (char*)d_ws;
    ushort_t* F    = (ushort_t*)ws;                                   // 32768*3584*2
    ushort_t* WT   = (ushort_t*)(ws + 234881024);                     // 4096*3584*2
    ushort_t* Cbuf = (ushort_t*)(ws + 234881024 + 29360128);          // 32768*6144*2
    float*    bias = (float*)   (ws + 234881024 + 29360128 + 402653184); // 6144*4

    hipLaunchKernelGGL(pack_wt_kernel, dim3(2048, 3), dim3(256), 0, stream,
                       W_a, Wg_a, W_b, Wg_b, W_c, Wg_c, WT);
    hipLaunchKernelGGL(pack_bias_kernel, dim3(24), dim3(256), 0, stream,
                       b_a, b_b, b_c, bg_a, bg_b, bg_c, bias);
    hipLaunchKernelGGL(ln_relu_kernel, dim3(32768, 3), dim3(256), 0, stream,
                       x_a, x_b, x_c, lnw_a, lnw_b, lnw_c, lnb_a, lnb_b, lnb_c, F);
    hipLaunchKernelGGL(gemm_kernel, dim3(3072), dim3(512), 131072, stream,
                       F, WT, bias, Cbuf);
    hipLaunchKernelGGL(fuse_kernel, dim3(16384), dim3(256), 0, stream,
                       Cbuf, (float*)d_out);
}